// Round 7
// baseline (205.852 us; speedup 1.0000x reference)
//
#include <hip/hip_runtime.h>
#include <hip/hip_bf16.h>

#define BB 2
#define SS 2048
#define EE 1024
#define HH 16
#define DD 64
#define MT (BB*SS)     // 4096 tokens
#define NQ (3*EE)      // 3072

typedef unsigned short u16;
typedef __bf16 bf16t;
typedef bf16t bf16x8 __attribute__((ext_vector_type(8)));
typedef short short8v __attribute__((ext_vector_type(8)));
typedef float f32x4 __attribute__((ext_vector_type(4)));

#define AS1 __attribute__((address_space(1)))
#define AS3 __attribute__((address_space(3)))

__device__ __forceinline__ u16 f2b(float f) {
  unsigned u = __builtin_bit_cast(unsigned, f);
  u += 0x7FFF + ((u >> 16) & 1);   // RNE
  return (u16)(u >> 16);
}

__device__ __forceinline__ unsigned cvtpk(float lo, float hi) {
  unsigned r;
  asm("v_cvt_pk_bf16_f32 %0, %1, %2" : "=v"(r) : "v"(lo), "v"(hi));
  return r;
}

__device__ __forceinline__ void gload_lds16(const void* g, void* l) {
  __builtin_amdgcn_global_load_lds((const AS1 void*)(g), (AS3 void*)(l), 16, 0, 0);
}

__device__ __forceinline__ f32x4 mfma_bf16(short8v a, short8v b, f32x4 c) {
  return __builtin_amdgcn_mfma_f32_16x16x32_bf16(
      __builtin_bit_cast(bf16x8, a), __builtin_bit_cast(bf16x8, b), c, 0, 0, 0);
}

// scale folded into Q: 1/sqrt(64) * log2(e)
#define QSCALE 0.18033688f

// ---------------- prologue: cast x -> bf16 ----------------
__global__ void __launch_bounds__(256) cast_kernel(const float* __restrict__ in,
                                                   u16* __restrict__ out, int n) {
  int i = (blockIdx.x * 256 + threadIdx.x) * 4;
  if (i + 3 < n) {
    float4 v = *(const float4*)(in + i);
    ushort4 o;
    o.x = f2b(v.x); o.y = f2b(v.y); o.z = f2b(v.z); o.w = f2b(v.w);
    *(ushort4*)(out + i) = o;
  }
}

// W [K][N] f32 -> WT [N][K] bf16, 64x64 LDS tile (coalesced both sides)
__global__ void __launch_bounds__(256) transpose_kernel(const float* __restrict__ W,
                                                        u16* __restrict__ WT,
                                                        int K, int N) {
  __shared__ float t[64][65];
  int k0 = blockIdx.y * 64, n0 = blockIdx.x * 64;
  int r = threadIdx.x >> 4;          // 0..15
  int c4 = (threadIdx.x & 15) * 4;   // 0..60
#pragma unroll
  for (int i = 0; i < 4; ++i) {
    float4 v = *(const float4*)(W + (size_t)(k0 + r + i * 16) * N + n0 + c4);
    t[r + i * 16][c4 + 0] = v.x; t[r + i * 16][c4 + 1] = v.y;
    t[r + i * 16][c4 + 2] = v.z; t[r + i * 16][c4 + 3] = v.w;
  }
  __syncthreads();
#pragma unroll
  for (int i = 0; i < 4; ++i) {
    ushort4 o;
    o.x = f2b(t[c4 + 0][r + i * 16]); o.y = f2b(t[c4 + 1][r + i * 16]);
    o.z = f2b(t[c4 + 2][r + i * 16]); o.w = f2b(t[c4 + 3][r + i * 16]);
    *(ushort4*)(WT + (size_t)(n0 + r + i * 16) * K + k0 + c4) = o;
  }
}

// ---------------- QKV GEMM: C[4096,3072] = x @ Wqkv + b, scatter to Q,K,Vt ----------------
__global__ void __launch_bounds__(256) gemm_qkv_kernel(
    const u16* __restrict__ A, const u16* __restrict__ BT,
    const float* __restrict__ bias,
    u16* __restrict__ Qs, u16* __restrict__ Ks, u16* __restrict__ Vt) {
  __shared__ u16 As[4096];
  __shared__ u16 Bs[4096];
  const int K = EE;
  int tid = threadIdx.x;
  int w = tid >> 6, lane = tid & 63;
  int g = lane >> 4, q = lane & 15;
  int m0 = blockIdx.y * 128, n0 = blockIdx.x * 128;
  int wm = (w >> 1) * 64, wn = (w & 1) * 64;

  f32x4 acc[4][4] = {};

  int r = tid >> 2;
  int kc = (tid & 3) * 8;
  const u16* ga = A + (size_t)(m0 + r) * K + kc;
  const u16* gb = BT + (size_t)(n0 + r) * K + kc;
  u16* lA0 = As + w * 512;
  u16* lA1 = As + 2048 + w * 512;
  u16* lB0 = Bs + w * 512;
  u16* lB1 = Bs + 2048 + w * 512;

  for (int k0 = 0; k0 < K; k0 += 32) {
    gload_lds16(ga, lA0);
    gload_lds16(ga + 64 * K, lA1);
    gload_lds16(gb, lB0);
    gload_lds16(gb + 64 * K, lB1);
    ga += 32; gb += 32;
    __syncthreads();
    short8v af[4], bfv[4];
#pragma unroll
    for (int m = 0; m < 4; ++m)
      af[m] = *(const short8v*)(As + (wm + m * 16 + q) * 32 + g * 8);
#pragma unroll
    for (int n = 0; n < 4; ++n)
      bfv[n] = *(const short8v*)(Bs + (wn + n * 16 + q) * 32 + g * 8);
#pragma unroll
    for (int m = 0; m < 4; ++m)
#pragma unroll
      for (int n = 0; n < 4; ++n)
        acc[m][n] = mfma_bf16(af[m], bfv[n], acc[m][n]);
    __syncthreads();
  }

#pragma unroll
  for (int m = 0; m < 4; ++m) {
    int row0 = m0 + wm + m * 16 + g * 4;
#pragma unroll
    for (int n = 0; n < 4; ++n) {
      int col = n0 + wn + n * 16 + q;
      float bi = bias[col];
      int t = col >> 10;
      int h = (col >> 6) & 15;
      int d = col & 63;
#pragma unroll
      for (int r2 = 0; r2 < 4; ++r2) {
        int row = row0 + r2;
        int b = row >> 11, s = row & 2047;
        float v = acc[m][n][r2] + bi;
        size_t bh = (size_t)b * HH + h;
        if (t == 0)      Qs[(bh * SS + s) * DD + d] = f2b(v * QSCALE);
        else if (t == 1) Ks[(bh * SS + s) * DD + d] = f2b(v);
        else             Vt[(bh * DD + d) * SS + s] = f2b(v);
      }
    }
  }
}

// ---------------- causal flash attention (swapped QK^T, LPT 1-wave blocks) ---
// Job = one 32-row q-chunk c (tiles = c/2+1). 2048 one-wave blocks ordered
// longest-first (c descending): ~8x block oversubscription per CU -> LPT
// backfill, ~4 waves/SIMD sustained, no tail. Barrier-free; K/V direct from
// global (L2-resident, 4 heads/XCD). S^T = mfma(K,Q) keeps q-rows lane-local
// (2-shuffle row reduce); P packed via cvt_pk into swizzled LDS; O^T =
// mfma(V^T,P). Defer-max (THR=8): skip oacc/lrun rescale when max growth <= 8.
__global__ void __launch_bounds__(64, 4) attn_kernel(
    const u16* __restrict__ Qg, const u16* __restrict__ Kg,
    const u16* __restrict__ Vg, u16* __restrict__ O) {
  __shared__ char lds[4096];           // 32x64 bf16 P buffer, swizzled
  int lane = threadIdx.x;
  int g = lane >> 4, q = lane & 15;
  int id = blockIdx.x;                 // 0..2047
  int c = 63 - (id >> 5);              // LPT: long chunks dispatch first
  int bh = id & 31;                    // id%8 -> XCD: 4 heads per XCD
  int qw = c * 32;
  char* Pw = lds;
  int qsw = (q & 7) << 4;              // P swizzle for this lane's rows

  const char* Qp = (const char*)Qg + (size_t)bh * (SS * 128);
  const char* Kp = (const char*)Kg + (size_t)bh * (SS * 128);
  const char* Vp = (const char*)Vg + (size_t)bh * (SS * 128);  // [d][s]
  int b = bh >> 4, h = bh & 15;

  short8v aq[2][2];
#pragma unroll
  for (int m = 0; m < 2; ++m)
#pragma unroll
    for (int j = 0; j < 2; ++j)
      aq[m][j] = *(const short8v*)(Qp + (size_t)(qw + m * 16 + q) * 128 + j * 64 + g * 16);

  f32x4 oacc[2][4] = {};               // O^T[d=vfi*16+g*4+r2][qrow=m*16+q]
  float mrun[2], lrun[2];
#pragma unroll
  for (int m = 0; m < 2; ++m) { mrun[m] = -1e30f; lrun[m] = 0.f; }

  const int nt = (qw >> 6) + 1;
  for (int t = 0; t < nt; ++t) {
    int kv0 = t << 6;
    // ---- K fragments (L2-hot) ----
    short8v kf[4][2];
#pragma unroll
    for (int cc = 0; cc < 4; ++cc) {
      const char* kp = Kp + (size_t)(kv0 + cc * 16 + q) * 128 + g * 16;
      kf[cc][0] = *(const short8v*)kp;
      kf[cc][1] = *(const short8v*)(kp + 64);
    }
    // ---- S^T = K Q^T : lane holds S[qw+m*16+q][kv0 + cc*16 + g*4 + r2] ----
    f32x4 st[2][4];
#pragma unroll
    for (int m = 0; m < 2; ++m)
#pragma unroll
      for (int cc = 0; cc < 4; ++cc) {
        f32x4 z = {};
        z = mfma_bf16(kf[cc][0], aq[m][0], z);
        z = mfma_bf16(kf[cc][1], aq[m][1], z);
        st[m][cc] = z;
      }
    // ---- V^T fragments (issue early; latency hides under softmax) ----
    short8v vf[4][2];
#pragma unroll
    for (int v = 0; v < 4; ++v) {
      const char* vp = Vp + (size_t)(v * 16 + q) * (SS * 2) + (size_t)kv0 * 2 + g * 16;
      vf[v][0] = *(const short8v*)vp;
      vf[v][1] = *(const short8v*)(vp + 64);
    }
    // ---- causal mask (diagonal tile only) ----
    if (kv0 + 63 > qw) {
#pragma unroll
      for (int m = 0; m < 2; ++m) {
        int row = qw + m * 16 + q;
#pragma unroll
        for (int cc = 0; cc < 4; ++cc) {
          int kvb = kv0 + cc * 16 + g * 4;
#pragma unroll
          for (int r2 = 0; r2 < 4; ++r2)
            if (kvb + r2 > row) st[m][cc][r2] = -1e30f;
        }
      }
    }
    // ---- online softmax (base-2; row lane-local, 2 shuffles) + defer-max ----
#pragma unroll
    for (int m = 0; m < 2; ++m) {
      f32x4 t01, t23;
#pragma unroll
      for (int r2 = 0; r2 < 4; ++r2) {
        t01[r2] = fmaxf(st[m][0][r2], st[m][1][r2]);
        t23[r2] = fmaxf(st[m][2][r2], st[m][3][r2]);
      }
      float mx = fmaxf(fmaxf(fmaxf(t01[0], t01[1]), fmaxf(t01[2], t01[3])),
                       fmaxf(fmaxf(t23[0], t23[1]), fmaxf(t23[2], t23[3])));
      mx = fmaxf(mx, __shfl_xor(mx, 16));
      mx = fmaxf(mx, __shfl_xor(mx, 32));
      if (!__all(mx - mrun[m] <= 8.f)) {   // T13: rescale only on real growth
        float mnew = fmaxf(mrun[m], mx);
        float alpha = exp2f(mrun[m] - mnew);
        mrun[m] = mnew;
        lrun[m] *= alpha;
#pragma unroll
        for (int vfi = 0; vfi < 4; ++vfi)
#pragma unroll
          for (int r2 = 0; r2 < 4; ++r2) oacc[m][vfi][r2] *= alpha;
      }
      f32x4 sum4 = {};
#pragma unroll
      for (int cc = 0; cc < 4; ++cc)
#pragma unroll
        for (int r2 = 0; r2 < 4; ++r2) {
          float pv = exp2f(st[m][cc][r2] - mrun[m]);
          st[m][cc][r2] = pv;
          sum4[r2] += pv;
        }
      float s = (sum4[0] + sum4[1]) + (sum4[2] + sum4[3]);
      s += __shfl_xor(s, 16);
      s += __shfl_xor(s, 32);
      lrun[m] += s;
      // ---- P -> LDS packed bf16x2 (row = m*16+q, kv-contig) ----
      char* base = Pw + (m * 16 + q) * 128;
#pragma unroll
      for (int cc = 0; cc < 4; ++cc) {
        unsigned p01 = cvtpk(st[m][cc][0], st[m][cc][1]);
        unsigned p23 = cvtpk(st[m][cc][2], st[m][cc][3]);
        *(unsigned*)(base + ((32 * cc + 8 * g + 0) ^ qsw)) = p01;
        *(unsigned*)(base + ((32 * cc + 8 * g + 4) ^ qsw)) = p23;
      }
      short8v pa0 = *(const short8v*)(base + ((g * 16) ^ qsw));
      short8v pa1 = *(const short8v*)(base + ((64 + g * 16) ^ qsw));
      // ---- O^T += V^T P ----
#pragma unroll
      for (int vfi = 0; vfi < 4; ++vfi) {
        oacc[m][vfi] = mfma_bf16(vf[vfi][0], pa0, oacc[m][vfi]);
        oacc[m][vfi] = mfma_bf16(vf[vfi][1], pa1, oacc[m][vfi]);
      }
    }
  }

#pragma unroll
  for (int m = 0; m < 2; ++m) {
    float inv = 1.0f / lrun[m];
    int row = qw + m * 16 + q;
    char* obase = (char*)O + (((size_t)b * SS + row) * EE + h * 64) * 2;
#pragma unroll
    for (int vfi = 0; vfi < 4; ++vfi) {
      uint2 o;
      o.x = cvtpk(oacc[m][vfi][0] * inv, oacc[m][vfi][1] * inv);
      o.y = cvtpk(oacc[m][vfi][2] * inv, oacc[m][vfi][3] * inv);
      *(uint2*)(obase + (vfi * 16 + g * 4) * 2) = o;
    }
  }
}

// ---------------- output projection GEMM: out[4096,1024] = O @ Wout + bout (f32) ----------------
__global__ void __launch_bounds__(256) gemm_out_kernel(
    const u16* __restrict__ A, const u16* __restrict__ BT,
    const float* __restrict__ bias, float* __restrict__ Cout) {
  __shared__ u16 As[4096];
  __shared__ u16 Bs[4096];
  const int K = EE;
  int tid = threadIdx.x;
  int w = tid >> 6, lane = tid & 63;
  int g = lane >> 4, q = lane & 15;
  int m0 = blockIdx.y * 128, n0 = blockIdx.x * 128;
  int wm = (w >> 1) * 64, wn = (w & 1) * 64;

  f32x4 acc[4][4] = {};

  int r = tid >> 2;
  int kc = (tid & 3) * 8;
  const u16* ga = A + (size_t)(m0 + r) * K + kc;
  const u16* gb = BT + (size_t)(n0 + r) * K + kc;
  u16* lA0 = As + w * 512;
  u16* lA1 = As + 2048 + w * 512;
  u16* lB0 = Bs + w * 512;
  u16* lB1 = Bs + 2048 + w * 512;

  for (int k0 = 0; k0 < K; k0 += 32) {
    gload_lds16(ga, lA0);
    gload_lds16(ga + 64 * K, lA1);
    gload_lds16(gb, lB0);
    gload_lds16(gb + 64 * K, lB1);
    ga += 32; gb += 32;
    __syncthreads();
    short8v af[4], bfv[4];
#pragma unroll
    for (int m = 0; m < 4; ++m)
      af[m] = *(const short8v*)(As + (wm + m * 16 + q) * 32 + g * 8);
#pragma unroll
    for (int n = 0; n < 4; ++n)
      bfv[n] = *(const short8v*)(Bs + (wn + n * 16 + q) * 32 + g * 8);
#pragma unroll
    for (int m = 0; m < 4; ++m)
#pragma unroll
      for (int n = 0; n < 4; ++n)
        acc[m][n] = mfma_bf16(af[m], bfv[n], acc[m][n]);
    __syncthreads();
  }

#pragma unroll
  for (int m = 0; m < 4; ++m) {
    int row0 = m0 + wm + m * 16 + g * 4;
#pragma unroll
    for (int n = 0; n < 4; ++n) {
      int col = n0 + wn + n * 16 + q;
      float bi = bias[col];
#pragma unroll
      for (int r2 = 0; r2 < 4; ++r2) {
        int row = row0 + r2;
        Cout[(size_t)row * EE + col] = acc[m][n][r2] + bi;
      }
    }
  }
}

extern "C" void kernel_launch(void* const* d_in, const int* in_sizes, int n_in,
                              void* d_out, int out_size, void* d_ws, size_t ws_size,
                              hipStream_t stream) {
  (void)in_sizes; (void)n_in; (void)out_size; (void)ws_size;
  const float* x    = (const float*)d_in[0];
  const float* Wqkv = (const float*)d_in[1];
  const float* bqkv = (const float*)d_in[2];
  const float* Wout = (const float*)d_in[3];
  const float* bout = (const float*)d_in[4];
  float* out = (float*)d_out;

  char* p = (char*)d_ws;
  u16* xb  = (u16*)p; p += (size_t)MT * EE * 2;           // 8 MB
  u16* wqT = (u16*)p; p += (size_t)NQ * EE * 2;           // 6 MB
  u16* woT = (u16*)p; p += (size_t)EE * EE * 2;           // 2 MB
  u16* Qs  = (u16*)p; p += (size_t)BB * HH * SS * DD * 2; // 8 MB
  u16* Ks  = (u16*)p; p += (size_t)BB * HH * SS * DD * 2; // 8 MB
  u16* Vt  = (u16*)p; p += (size_t)BB * HH * DD * SS * 2; // 8 MB
  u16* Ob  = (u16*)p; p += (size_t)MT * EE * 2;           // 8 MB

  cast_kernel<<<dim3((MT * EE / 4) / 256), dim3(256), 0, stream>>>(x, xb, MT * EE);
  transpose_kernel<<<dim3(NQ / 64, EE / 64), dim3(256), 0, stream>>>(Wqkv, wqT, EE, NQ);
  transpose_kernel<<<dim3(EE / 64, EE / 64), dim3(256), 0, stream>>>(Wout, woT, EE, EE);
  gemm_qkv_kernel<<<dim3(NQ / 128, MT / 128), dim3(256), 0, stream>>>(xb, wqT, bqkv, Qs, Ks, Vt);
  attn_kernel<<<dim3(2048), dim3(64), 0, stream>>>(Qs, Ks, Vt, Ob);
  gemm_out_kernel<<<dim3(EE / 128, MT / 128), dim3(256), 0, stream>>>(Ob, woT, bout, out);
}

// Round 8
// 147.346 us; speedup vs baseline: 1.3971x; 1.3971x over previous
//
#include <hip/hip_runtime.h>
#include <hip/hip_bf16.h>

#define BB 2
#define SS 2048
#define EE 1024
#define HH 16
#define DD 64
#define MT (BB*SS)     // 4096 tokens
#define NQ (3*EE)      // 3072

typedef unsigned short u16;
typedef __bf16 bf16t;
typedef bf16t bf16x8 __attribute__((ext_vector_type(8)));
typedef short short8v __attribute__((ext_vector_type(8)));
typedef float f32x4 __attribute__((ext_vector_type(4)));

#define AS1 __attribute__((address_space(1)))
#define AS3 __attribute__((address_space(3)))

__device__ __forceinline__ u16 f2b(float f) {
  unsigned u = __builtin_bit_cast(unsigned, f);
  u += 0x7FFF + ((u >> 16) & 1);   // RNE
  return (u16)(u >> 16);
}

__device__ __forceinline__ unsigned cvtpk(float lo, float hi) {
  unsigned r;
  asm("v_cvt_pk_bf16_f32 %0, %1, %2" : "=v"(r) : "v"(lo), "v"(hi));
  return r;
}

__device__ __forceinline__ void gload_lds16(const void* g, void* l) {
  __builtin_amdgcn_global_load_lds((const AS1 void*)(g), (AS3 void*)(l), 16, 0, 0);
}

__device__ __forceinline__ f32x4 mfma_bf16(short8v a, short8v b, f32x4 c) {
  return __builtin_amdgcn_mfma_f32_16x16x32_bf16(
      __builtin_bit_cast(bf16x8, a), __builtin_bit_cast(bf16x8, b), c, 0, 0, 0);
}

// scale folded into Q: 1/sqrt(64) * log2(e)
#define QSCALE 0.18033688f

// ---------------- prologue: cast x -> bf16 ----------------
__global__ void __launch_bounds__(256) cast_kernel(const float* __restrict__ in,
                                                   u16* __restrict__ out, int n) {
  int i = (blockIdx.x * 256 + threadIdx.x) * 4;
  if (i + 3 < n) {
    float4 v = *(const float4*)(in + i);
    ushort4 o;
    o.x = f2b(v.x); o.y = f2b(v.y); o.z = f2b(v.z); o.w = f2b(v.w);
    *(ushort4*)(out + i) = o;
  }
}

// W [K][N] f32 -> WT [N][K] bf16, 64x64 LDS tile (coalesced both sides)
__global__ void __launch_bounds__(256) transpose_kernel(const float* __restrict__ W,
                                                        u16* __restrict__ WT,
                                                        int K, int N) {
  __shared__ float t[64][65];
  int k0 = blockIdx.y * 64, n0 = blockIdx.x * 64;
  int r = threadIdx.x >> 4;          // 0..15
  int c4 = (threadIdx.x & 15) * 4;   // 0..60
#pragma unroll
  for (int i = 0; i < 4; ++i) {
    float4 v = *(const float4*)(W + (size_t)(k0 + r + i * 16) * N + n0 + c4);
    t[r + i * 16][c4 + 0] = v.x; t[r + i * 16][c4 + 1] = v.y;
    t[r + i * 16][c4 + 2] = v.z; t[r + i * 16][c4 + 3] = v.w;
  }
  __syncthreads();
#pragma unroll
  for (int i = 0; i < 4; ++i) {
    ushort4 o;
    o.x = f2b(t[c4 + 0][r + i * 16]); o.y = f2b(t[c4 + 1][r + i * 16]);
    o.z = f2b(t[c4 + 2][r + i * 16]); o.w = f2b(t[c4 + 3][r + i * 16]);
    *(ushort4*)(WT + (size_t)(n0 + r + i * 16) * K + k0 + c4) = o;
  }
}

// ---------------- QKV GEMM: C[4096,3072] = x @ Wqkv + b, scatter to Q,K,Vt ----------------
__global__ void __launch_bounds__(256) gemm_qkv_kernel(
    const u16* __restrict__ A, const u16* __restrict__ BT,
    const float* __restrict__ bias,
    u16* __restrict__ Qs, u16* __restrict__ Ks, u16* __restrict__ Vt) {
  __shared__ u16 As[4096];
  __shared__ u16 Bs[4096];
  const int K = EE;
  int tid = threadIdx.x;
  int w = tid >> 6, lane = tid & 63;
  int g = lane >> 4, q = lane & 15;
  int m0 = blockIdx.y * 128, n0 = blockIdx.x * 128;
  int wm = (w >> 1) * 64, wn = (w & 1) * 64;

  f32x4 acc[4][4] = {};

  int r = tid >> 2;
  int kc = (tid & 3) * 8;
  const u16* ga = A + (size_t)(m0 + r) * K + kc;
  const u16* gb = BT + (size_t)(n0 + r) * K + kc;
  u16* lA0 = As + w * 512;
  u16* lA1 = As + 2048 + w * 512;
  u16* lB0 = Bs + w * 512;
  u16* lB1 = Bs + 2048 + w * 512;

  for (int k0 = 0; k0 < K; k0 += 32) {
    gload_lds16(ga, lA0);
    gload_lds16(ga + 64 * K, lA1);
    gload_lds16(gb, lB0);
    gload_lds16(gb + 64 * K, lB1);
    ga += 32; gb += 32;
    __syncthreads();
    short8v af[4], bfv[4];
#pragma unroll
    for (int m = 0; m < 4; ++m)
      af[m] = *(const short8v*)(As + (wm + m * 16 + q) * 32 + g * 8);
#pragma unroll
    for (int n = 0; n < 4; ++n)
      bfv[n] = *(const short8v*)(Bs + (wn + n * 16 + q) * 32 + g * 8);
#pragma unroll
    for (int m = 0; m < 4; ++m)
#pragma unroll
      for (int n = 0; n < 4; ++n)
        acc[m][n] = mfma_bf16(af[m], bfv[n], acc[m][n]);
    __syncthreads();
  }

#pragma unroll
  for (int m = 0; m < 4; ++m) {
    int row0 = m0 + wm + m * 16 + g * 4;
#pragma unroll
    for (int n = 0; n < 4; ++n) {
      int col = n0 + wn + n * 16 + q;
      float bi = bias[col];
      int t = col >> 10;
      int h = (col >> 6) & 15;
      int d = col & 63;
#pragma unroll
      for (int r2 = 0; r2 < 4; ++r2) {
        int row = row0 + r2;
        int b = row >> 11, s = row & 2047;
        float v = acc[m][n][r2] + bi;
        size_t bh = (size_t)b * HH + h;
        if (t == 0)      Qs[(bh * SS + s) * DD + d] = f2b(v * QSCALE);
        else if (t == 1) Ks[(bh * SS + s) * DD + d] = f2b(v);
        else             Vt[(bh * DD + d) * SS + s] = f2b(v);
      }
    }
  }
}

// ---------------- causal flash attention (swapped QK^T + K reg dbuf) --------
// Round-5 structure (best measured): 4 waves x 32 q-rows, barrier-free, K/V
// direct from global (L2-resident, 4 heads/XCD via bh=b0&31 -> XCD=bh%8),
// complementary qt pairing per CU. NEW: K fragments double-buffered in
// registers -- K(t+1) issued between QK^T(t) and softmax(t), so its L2
// latency hides under ~1500cy of softmax+pack+PV. Defer-max (THR=8) skips
// the oacc rescale when the running max grows by <= 8 (P bounded by 2^8).
__global__ void __launch_bounds__(256) attn_kernel(
    const u16* __restrict__ Qg, const u16* __restrict__ Kg,
    const u16* __restrict__ Vg, u16* __restrict__ O) {
  __shared__ char lds[16384];          // per-wave 4KB P buffer (32x64 bf16, swizzled)
  int tid = threadIdx.x;
  int w = tid >> 6, lane = tid & 63;
  int g = lane >> 4, q = lane & 15;
  int b0 = blockIdx.x;
  int bh, qt;
  if (b0 < 256) { bh = b0 & 31; qt = b0 >> 5; }
  else          { bh = (b0 - 256) & 31; qt = 15 - ((b0 - 256) >> 5); }
  int qw = qt * 128 + w * 32;          // wave's first q row
  char* Pw = lds + w * 4096;
  int qsw = (q & 7) << 4;              // P swizzle for this lane's rows

  const char* Qp = (const char*)Qg + (size_t)bh * (SS * 128);
  const char* Kp = (const char*)Kg + (size_t)bh * (SS * 128);
  const char* Vp = (const char*)Vg + (size_t)bh * (SS * 128);  // [d][s]

  short8v aq[2][2];
#pragma unroll
  for (int m = 0; m < 2; ++m)
#pragma unroll
    for (int j = 0; j < 2; ++j)
      aq[m][j] = *(const short8v*)(Qp + (size_t)(qw + m * 16 + q) * 128 + j * 64 + g * 16);

  f32x4 oacc[2][4] = {};               // O^T[d=vfi*16+g*4+r2][qrow=m*16+q]
  float mrun[2], lrun[2];
#pragma unroll
  for (int m = 0; m < 2; ++m) { mrun[m] = -1e30f; lrun[m] = 0.f; }

  const int nt = (qw >> 6) + 1;

  short8v kfA[4][2], kfB[4][2];

  auto loadK = [&](short8v (&kf)[4][2], int kv0) {
#pragma unroll
    for (int cc = 0; cc < 4; ++cc) {
      const char* kp = Kp + (size_t)(kv0 + cc * 16 + q) * 128 + g * 16;
      kf[cc][0] = *(const short8v*)kp;
      kf[cc][1] = *(const short8v*)(kp + 64);
    }
  };

  auto tileBody = [&](short8v (&kf)[4][2], short8v (&kfn)[4][2], int t, bool pref) {
    int kv0 = t << 6;
    // ---- V^T fragments (independent; latency hides under QK^T+softmax) ----
    short8v vf[4][2];
#pragma unroll
    for (int v = 0; v < 4; ++v) {
      const char* vp = Vp + (size_t)(v * 16 + q) * (SS * 2) + (size_t)kv0 * 2 + g * 16;
      vf[v][0] = *(const short8v*)vp;
      vf[v][1] = *(const short8v*)(vp + 64);
    }
    // ---- S^T = K Q^T : lane holds S[qw+m*16+q][kv0 + cc*16 + g*4 + r2] ----
    f32x4 st[2][4];
#pragma unroll
    for (int m = 0; m < 2; ++m)
#pragma unroll
      for (int cc = 0; cc < 4; ++cc) {
        f32x4 z = {};
        z = mfma_bf16(kf[cc][0], aq[m][0], z);
        z = mfma_bf16(kf[cc][1], aq[m][1], z);
        st[m][cc] = z;
      }
    // ---- prefetch next tile's K into the other register buffer ----
    if (pref) loadK(kfn, (t + 1) << 6);
    // ---- causal mask (diagonal tile only) ----
    if (kv0 + 63 > qw) {
#pragma unroll
      for (int m = 0; m < 2; ++m) {
        int row = qw + m * 16 + q;
#pragma unroll
        for (int cc = 0; cc < 4; ++cc) {
          int kvb = kv0 + cc * 16 + g * 4;
#pragma unroll
          for (int r2 = 0; r2 < 4; ++r2)
            if (kvb + r2 > row) st[m][cc][r2] = -1e30f;
        }
      }
    }
    // ---- online softmax (base-2; row lane-local, 2 shuffles) + defer-max ----
#pragma unroll
    for (int m = 0; m < 2; ++m) {
      f32x4 t01, t23;
#pragma unroll
      for (int r2 = 0; r2 < 4; ++r2) {
        t01[r2] = fmaxf(st[m][0][r2], st[m][1][r2]);
        t23[r2] = fmaxf(st[m][2][r2], st[m][3][r2]);
      }
      float mx = fmaxf(fmaxf(fmaxf(t01[0], t01[1]), fmaxf(t01[2], t01[3])),
                       fmaxf(fmaxf(t23[0], t23[1]), fmaxf(t23[2], t23[3])));
      mx = fmaxf(mx, __shfl_xor(mx, 16));
      mx = fmaxf(mx, __shfl_xor(mx, 32));
      if (!__all(mx - mrun[m] <= 8.f)) {   // T13: rescale only on real growth
        float mnew = fmaxf(mrun[m], mx);
        float alpha = exp2f(mrun[m] - mnew);
        mrun[m] = mnew;
        lrun[m] *= alpha;
#pragma unroll
        for (int vfi = 0; vfi < 4; ++vfi)
#pragma unroll
          for (int r2 = 0; r2 < 4; ++r2) oacc[m][vfi][r2] *= alpha;
      }
      f32x4 sum4 = {};
#pragma unroll
      for (int cc = 0; cc < 4; ++cc)
#pragma unroll
        for (int r2 = 0; r2 < 4; ++r2) {
          float pv = exp2f(st[m][cc][r2] - mrun[m]);
          st[m][cc][r2] = pv;
          sum4[r2] += pv;
        }
      float s = (sum4[0] + sum4[1]) + (sum4[2] + sum4[3]);
      s += __shfl_xor(s, 16);
      s += __shfl_xor(s, 32);
      lrun[m] += s;
      // ---- P -> LDS packed bf16x2 (row = m*16+q, kv-contig) ----
      char* base = Pw + (m * 16 + q) * 128;
#pragma unroll
      for (int cc = 0; cc < 4; ++cc) {
        unsigned p01 = cvtpk(st[m][cc][0], st[m][cc][1]);
        unsigned p23 = cvtpk(st[m][cc][2], st[m][cc][3]);
        *(unsigned*)(base + ((32 * cc + 8 * g + 0) ^ qsw)) = p01;
        *(unsigned*)(base + ((32 * cc + 8 * g + 4) ^ qsw)) = p23;
      }
      short8v pa0 = *(const short8v*)(base + ((g * 16) ^ qsw));
      short8v pa1 = *(const short8v*)(base + ((64 + g * 16) ^ qsw));
      // ---- O^T += V^T P ----
#pragma unroll
      for (int vfi = 0; vfi < 4; ++vfi) {
        oacc[m][vfi] = mfma_bf16(vf[vfi][0], pa0, oacc[m][vfi]);
        oacc[m][vfi] = mfma_bf16(vf[vfi][1], pa1, oacc[m][vfi]);
      }
    }
  };

  loadK(kfA, 0);
  for (int t = 0; t < nt; t += 2) {
    tileBody(kfA, kfB, t, t + 1 < nt);
    if (t + 1 < nt) tileBody(kfB, kfA, t + 1, t + 2 < nt);
  }

  int b = bh >> 4, h = bh & 15;
#pragma unroll
  for (int m = 0; m < 2; ++m) {
    float inv = 1.0f / lrun[m];
    int row = qw + m * 16 + q;
    char* obase = (char*)O + (((size_t)b * SS + row) * EE + h * 64) * 2;
#pragma unroll
    for (int vfi = 0; vfi < 4; ++vfi) {
      uint2 o;
      o.x = cvtpk(oacc[m][vfi][0] * inv, oacc[m][vfi][1] * inv);
      o.y = cvtpk(oacc[m][vfi][2] * inv, oacc[m][vfi][3] * inv);
      *(uint2*)(obase + (vfi * 16 + g * 4) * 2) = o;
    }
  }
}

// ---------------- output projection GEMM: out[4096,1024] = O @ Wout + bout (f32) ----------------
__global__ void __launch_bounds__(256) gemm_out_kernel(
    const u16* __restrict__ A, const u16* __restrict__ BT,
    const float* __restrict__ bias, float* __restrict__ Cout) {
  __shared__ u16 As[4096];
  __shared__ u16 Bs[4096];
  const int K = EE;
  int tid = threadIdx.x;
  int w = tid >> 6, lane = tid & 63;
  int g = lane >> 4, q = lane & 15;
  int m0 = blockIdx.y * 128, n0 = blockIdx.x * 128;
  int wm = (w >> 1) * 64, wn = (w & 1) * 64;

  f32x4 acc[4][4] = {};

  int r = tid >> 2;
  int kc = (tid & 3) * 8;
  const u16* ga = A + (size_t)(m0 + r) * K + kc;
  const u16* gb = BT + (size_t)(n0 + r) * K + kc;
  u16* lA0 = As + w * 512;
  u16* lA1 = As + 2048 + w * 512;
  u16* lB0 = Bs + w * 512;
  u16* lB1 = Bs + 2048 + w * 512;

  for (int k0 = 0; k0 < K; k0 += 32) {
    gload_lds16(ga, lA0);
    gload_lds16(ga + 64 * K, lA1);
    gload_lds16(gb, lB0);
    gload_lds16(gb + 64 * K, lB1);
    ga += 32; gb += 32;
    __syncthreads();
    short8v af[4], bfv[4];
#pragma unroll
    for (int m = 0; m < 4; ++m)
      af[m] = *(const short8v*)(As + (wm + m * 16 + q) * 32 + g * 8);
#pragma unroll
    for (int n = 0; n < 4; ++n)
      bfv[n] = *(const short8v*)(Bs + (wn + n * 16 + q) * 32 + g * 8);
#pragma unroll
    for (int m = 0; m < 4; ++m)
#pragma unroll
      for (int n = 0; n < 4; ++n)
        acc[m][n] = mfma_bf16(af[m], bfv[n], acc[m][n]);
    __syncthreads();
  }

#pragma unroll
  for (int m = 0; m < 4; ++m) {
    int row0 = m0 + wm + m * 16 + g * 4;
#pragma unroll
    for (int n = 0; n < 4; ++n) {
      int col = n0 + wn + n * 16 + q;
      float bi = bias[col];
#pragma unroll
      for (int r2 = 0; r2 < 4; ++r2) {
        int row = row0 + r2;
        Cout[(size_t)row * EE + col] = acc[m][n][r2] + bi;
      }
    }
  }
}

extern "C" void kernel_launch(void* const* d_in, const int* in_sizes, int n_in,
                              void* d_out, int out_size, void* d_ws, size_t ws_size,
                              hipStream_t stream) {
  (void)in_sizes; (void)n_in; (void)out_size; (void)ws_size;
  const float* x    = (const float*)d_in[0];
  const float* Wqkv = (const float*)d_in[1];
  const float* bqkv = (const float*)d_in[2];
  const float* Wout = (const float*)d_in[3];
  const float* bout = (const float*)d_in[4];
  float* out = (float*)d_out;

  char* p = (char*)d_ws;
  u16* xb  = (u16*)p; p += (size_t)MT * EE * 2;           // 8 MB
  u16* wqT = (u16*)p; p += (size_t)NQ * EE * 2;           // 6 MB
  u16* woT = (u16*)p; p += (size_t)EE * EE * 2;           // 2 MB
  u16* Qs  = (u16*)p; p += (size_t)BB * HH * SS * DD * 2; // 8 MB
  u16* Ks  = (u16*)p; p += (size_t)BB * HH * SS * DD * 2; // 8 MB
  u16* Vt  = (u16*)p; p += (size_t)BB * HH * DD * SS * 2; // 8 MB
  u16* Ob  = (u16*)p; p += (size_t)MT * EE * 2;           // 8 MB

  cast_kernel<<<dim3((MT * EE / 4) / 256), dim3(256), 0, stream>>>(x, xb, MT * EE);
  transpose_kernel<<<dim3(NQ / 64, EE / 64), dim3(256), 0, stream>>>(Wqkv, wqT, EE, NQ);
  transpose_kernel<<<dim3(EE / 64, EE / 64), dim3(256), 0, stream>>>(Wout, woT, EE, EE);
  gemm_qkv_kernel<<<dim3(NQ / 128, MT / 128), dim3(256), 0, stream>>>(xb, wqT, bqkv, Qs, Ks, Vt);
  attn_kernel<<<dim3(512), dim3(256), 0, stream>>>(Qs, Ks, Vt, Ob);
  gemm_out_kernel<<<dim3(EE / 128, MT / 128), dim3(256), 0, stream>>>(Ob, woT, bout, out);
}